// Round 5
// baseline (253.537 us; speedup 1.0000x reference)
//
#include <hip/hip_runtime.h>
#include <hip/hip_bf16.h>

#define N_ 32
#define C_ 128
#define H_ 48
#define W_ 48
#define P_ (H_*W_)   // 2304
#define K_ 64
#define S_ 4
#define L_ 3
#define R_ 21
#define NB_ 72       // P_/32 pixel tiles per image
#define M_ 512       // total logit rows

typedef __hip_bfloat16 bf16;
typedef __attribute__((ext_vector_type(8))) short   bf16x8;
typedef __attribute__((ext_vector_type(8))) unsigned short u16x8;
typedef __attribute__((ext_vector_type(4))) float   f32x4;

__device__ __forceinline__ float b2f(bf16 v){ return __bfloat162float(v); }
__device__ __forceinline__ float u2f(unsigned short u){
  union { unsigned i; float f; } v; v.i = ((unsigned)u) << 16; return v.f;
}
__device__ __forceinline__ unsigned short f2u(float f){
  bf16 h = __float2bfloat16(f);
  return *(unsigned short*)&h;
}

// ---------- dtype probe: flag=1 if inputs are fp32, 0 if bf16 ----------
__global__ __launch_bounds__(256) void k_probe(const unsigned short* __restrict__ xb,
                                               int* __restrict__ flag){
  int t = threadIdx.x;
  int weird = 0;
  for (int i = t; i < 4096; i += 256){
    int e = (xb[i] >> 7) & 0xFF;
    if (e >= 0x8E) weird++;
  }
  __shared__ int s[256];
  s[t] = weird; __syncthreads();
  for (int o = 128; o > 0; o >>= 1){ if (t < o) s[t] += s[t+o]; __syncthreads(); }
  if (t == 0) flag[0] = (s[0] > 64) ? 1 : 0;
}

// ---------- build Wall[512][128] bf16: rows 0-63 score, 64-319 shadow, 320-511 app ----------
__global__ __launch_bounds__(256) void k_wall(const void* __restrict__ cvw, const void* __restrict__ csw,
                                              const void* __restrict__ caw, const int* __restrict__ flag,
                                              bf16* __restrict__ Wall){
  int i = blockIdx.x*256 + threadIdx.x;          // 0..65535
  int f32 = flag[0];
  float v;
  if (i < 8192)       v = f32 ? ((const float*)cvw)[i]        : b2f(((const bf16*)cvw)[i]);
  else if (i < 40960) v = f32 ? ((const float*)csw)[i-8192]   : b2f(((const bf16*)csw)[i-8192]);
  else                v = f32 ? ((const float*)caw)[i-40960]  : b2f(((const bf16*)caw)[i-40960]);
  Wall[i] = __float2bfloat16(v);
}

// ---------- K1: per-pixel L2 norm -> xnT[n][p][c] bf16 (pixel-major, MFMA-B-ready) ----------
__global__ __launch_bounds__(256) void k_norm(const void* __restrict__ x,
                                              const int* __restrict__ flag,
                                              bf16* __restrict__ xnT){
  int idx = blockIdx.x*256 + threadIdx.x;        // n*P + p
  int n = idx / P_, p = idx - n*P_;
  int f32 = flag[0];
  float ss = 0.f;
  if (f32){
    const float* xc = (const float*)x + (size_t)n*C_*P_ + p;
    #pragma unroll 8
    for (int c=0;c<C_;++c){ float v = xc[(size_t)c*P_]; ss += v*v; }
    float invn = 1.f / fmaxf(sqrtf(ss), 1e-12f);
    bf16* xo = xnT + ((size_t)n*P_ + p)*C_;
    for (int c8=0;c8<C_;c8+=8){
      u16x8 pk;
      #pragma unroll
      for (int j=0;j<8;++j) pk[j] = f2u(xc[(size_t)(c8+j)*P_] * invn);
      *(u16x8*)(xo + c8) = pk;
    }
  } else {
    const bf16* xc = (const bf16*)x + (size_t)n*C_*P_ + p;
    #pragma unroll 8
    for (int c=0;c<C_;++c){ float v = b2f(xc[(size_t)c*P_]); ss += v*v; }
    float invn = 1.f / fmaxf(sqrtf(ss), 1e-12f);
    bf16* xo = xnT + ((size_t)n*P_ + p)*C_;
    for (int c8=0;c8<C_;c8+=8){
      u16x8 pk;
      #pragma unroll
      for (int j=0;j<8;++j) pk[j] = f2u(b2f(xc[(size_t)(c8+j)*P_]) * invn);
      *(u16x8*)(xo + c8) = pk;
    }
  }
}

// ---------- K2: fused 512-row MFMA GEMM; softmax/shadow -> tiled a; relu(app) -> tiled g ----------
// grid (NB_=72, N_=32), 256 threads (4 waves). Wave w owns rows [w*128, w*128+128).
// tiled layouts: a_t[(n*NB+pb)*64 + k][32px] ushort; g_t[(n*NB+pb)*192 + lk][32px] ushort.
__global__ __launch_bounds__(256, 2) void k_gemm(const bf16* __restrict__ Wall,
                                                 const bf16* __restrict__ xnT,
                                                 unsigned short* __restrict__ a,
                                                 unsigned short* __restrict__ g){
  __shared__ float ldsL[M_][34];                 // 69632 B
  __shared__ float redA[32][8];
  __shared__ float redB[32][8];
  __shared__ __align__(16) unsigned short a_tile[K_*32];  // 4096 B
  int n = blockIdx.y, pb = blockIdx.x;
  int p0 = pb*32;
  int t = threadIdx.x, wv = t>>6, l = t&63;

  int mrow = l&15, quad = l>>4;
  const bf16* Abase = Wall + ((size_t)(wv*128 + mrow))*C_ + quad*8;
  const bf16* Bbase = xnT + ((size_t)n*P_ + p0 + mrow)*C_ + quad*8;

  f32x4 acc[8][2];
  #pragma unroll
  for (int rt=0;rt<8;++rt){ acc[rt][0] = (f32x4){0,0,0,0}; acc[rt][1] = (f32x4){0,0,0,0}; }

  #pragma unroll
  for (int k0=0;k0<C_;k0+=32){
    bf16x8 b0 = *(const bf16x8*)(Bbase + k0);
    bf16x8 b1 = *(const bf16x8*)(Bbase + 16*C_ + k0);
    #pragma unroll
    for (int rt=0;rt<8;++rt){
      bf16x8 af = *(const bf16x8*)(Abase + (size_t)rt*16*C_ + k0);
      acc[rt][0] = __builtin_amdgcn_mfma_f32_16x16x32_bf16(af, b0, acc[rt][0], 0,0,0);
      acc[rt][1] = __builtin_amdgcn_mfma_f32_16x16x32_bf16(af, b1, acc[rt][1], 0,0,0);
    }
  }
  // C/D layout: col = lane&15, row = quad*4 + reg
  #pragma unroll
  for (int rt=0;rt<8;++rt){
    int row0 = wv*128 + rt*16;
    #pragma unroll
    for (int ct=0;ct<2;++ct)
      #pragma unroll
      for (int r=0;r<4;++r)
        ldsL[row0 + quad*4 + r][ct*16 + mrow] = acc[rt][ct][r];
  }
  __syncthreads();

  // ---- softmax epilogue: thread t -> pixel px = t&31, cluster group g2 = t>>5 ----
  int px = t&31, g2 = t>>5;
  float sc[8];
  #pragma unroll
  for (int kk=0;kk<8;++kk) sc[kk] = ldsL[g2*8+kk][px];
  float pm = sc[0];
  #pragma unroll
  for (int kk=1;kk<8;++kk) pm = fmaxf(pm, sc[kk]);
  redA[px][g2] = pm;
  __syncthreads();
  float m = redA[px][0];
  #pragma unroll
  for (int i=1;i<8;++i) m = fmaxf(m, redA[px][i]);
  float ps = 0.f;
  #pragma unroll
  for (int kk=0;kk<8;++kk) ps += __expf(sc[kk]-m);
  redB[px][g2] = ps;
  __syncthreads();
  float Z = 0.f;
  #pragma unroll
  for (int i=0;i<8;++i) Z += redB[px][i];
  float invZ = 1.f / Z;

  #pragma unroll
  for (int kk=0;kk<8;++kk){
    int k = g2*8 + kk;
    float s0 = sc[kk];
    float sh0 = ldsL[64 + k*4 + 0][px];
    float sh1 = ldsL[64 + k*4 + 1][px];
    float sh2 = ldsL[64 + k*4 + 2][px];
    float sh3 = ldsL[64 + k*4 + 3][px];
    float m2 = fmaxf(fmaxf(fmaxf(fmaxf(s0, sh0), sh1), sh2), sh3);
    float e0 = __expf(s0-m2);
    float den = e0 + __expf(sh0-m2) + __expf(sh1-m2) + __expf(sh2-m2) + __expf(sh3-m2);
    a_tile[k*32 + px] = f2u(__expf(s0-m)*invZ * (e0/den));
  }
  __syncthreads();

  // ---- coalesced tiled stores ----
  size_t tile = (size_t)n*NB_ + pb;
  // a_t: 64 rows x 32 px ushort = 4 KB, 16 B per thread
  *(u16x8*)(a + tile*(K_*32) + t*8) = ((const u16x8*)a_tile)[t];
  // g_t: relu(app rows 320..511) -> 192 rows x 32 px ushort, 8 B per lane per iter
  unsigned short* gt = g + tile*(192*32);
  #pragma unroll
  for (int i=t;i<192*32/4;i+=256){
    int row = i>>3, q4 = (i&7)*4;
    ushort4 pk;
    pk.x = f2u(fmaxf(ldsL[320+row][q4+0], 0.f));
    pk.y = f2u(fmaxf(ldsL[320+row][q4+1], 0.f));
    pk.z = f2u(fmaxf(ldsL[320+row][q4+2], 0.f));
    pk.w = f2u(fmaxf(ldsL[320+row][q4+3], 0.f));
    *(ushort4*)(gt + i*4) = pk;
  }
}

// ---------- K3: region sums from tiled g -> sal[n][k][21]. One block per (n,k). ----------
__global__ __launch_bounds__(256) void k_sal2(const unsigned short* __restrict__ g,
                                              float* __restrict__ sal){
  int k = blockIdx.x, n = blockIdx.y, t = threadIdx.x;
  const unsigned short* gb = g + (size_t)n*NB_*(192*32);
  float acc[R_];
  #pragma unroll
  for (int r=0;r<R_;++r) acc[r] = 0.f;
  #pragma unroll
  for (int jj=0;jj<9;++jj){
    int p = t + jj*256;
    int pb = p>>5, px = p&31;
    int h = p/48, wc = p - h*48;
    const unsigned short* gt = gb + (size_t)pb*(192*32);
    acc[0] += u2f(gt[k*32 + px]);
    float v1 = u2f(gt[(64+k)*32 + px]);
    #pragma unroll
    for (int i=0;i<2;++i) if (h>=16*i && h<16*i+32)
      #pragma unroll
      for (int j=0;j<2;++j) if (wc>=16*j && wc<16*j+32) acc[1+2*i+j] += v1;
    float v2 = u2f(gt[(128+k)*32 + px]);
    #pragma unroll
    for (int i=0;i<4;++i) if (h>=10*i-1 && h<10*i+19)
      #pragma unroll
      for (int j=0;j<4;++j) if (wc>=10*j-1 && wc<10*j+19) acc[5+4*i+j] += v2;
  }
  #pragma unroll
  for (int r=0;r<R_;++r){
    float v = acc[r];
    #pragma unroll
    for (int o=32;o>0;o>>=1) v += __shfl_down(v, o);
    acc[r] = v;
  }
  __shared__ float s_part[4][R_];
  int wv = t>>6;
  if ((t&63) == 0){
    #pragma unroll
    for (int r=0;r<R_;++r) s_part[wv][r] = acc[r];
  }
  __syncthreads();
  if (t < R_)
    sal[((size_t)n*K_+k)*R_ + t] = s_part[0][t]+s_part[1][t]+s_part[2][t]+s_part[3][t];
}

// ---------- K4: vlad for 4 clusters per block ----------
__global__ __launch_bounds__(256) void k_vlad(const bf16* __restrict__ xnT,
                                              const unsigned short* __restrict__ a,
                                              const float* __restrict__ sal,
                                              const void* __restrict__ cen,
                                              const int* __restrict__ flag,
                                              float* __restrict__ vlad){
  __shared__ __align__(16) float s_aw[4][P_];    // 36864 B
  __shared__ float s_sal[4][R_];
  __shared__ __align__(16) float s_red[8][32][4];
  __shared__ float s_saw[4][4];
  int kq = blockIdx.x, n = blockIdx.y, t = threadIdx.x;
  int k0 = kq*4;
  int f32 = flag[0];
  if (t < 4*R_) ((float*)s_sal)[t] = sal[((size_t)n*K_+k0)*R_ + t];
  __syncthreads();
  float loc[4] = {0.f,0.f,0.f,0.f};
  #pragma unroll
  for (int jj=0;jj<9;++jj){
    int p = t + jj*256;
    int pb = p>>5, px = p&31;
    int h = p/48, wc = p - h*48;
    float w0 = s_sal[0][0], w1 = s_sal[1][0], w2 = s_sal[2][0], w3 = s_sal[3][0];
    #pragma unroll
    for (int i=0;i<2;++i) if (h>=16*i && h<16*i+32)
      #pragma unroll
      for (int j=0;j<2;++j) if (wc>=16*j && wc<16*j+32){
        int r = 1+2*i+j;
        w0 += s_sal[0][r]; w1 += s_sal[1][r]; w2 += s_sal[2][r]; w3 += s_sal[3][r];
      }
    #pragma unroll
    for (int i=0;i<4;++i) if (h>=10*i-1 && h<10*i+19)
      #pragma unroll
      for (int j=0;j<4;++j) if (wc>=10*j-1 && wc<10*j+19){
        int r = 5+4*i+j;
        w0 += s_sal[0][r]; w1 += s_sal[1][r]; w2 += s_sal[2][r]; w3 += s_sal[3][r];
      }
    const unsigned short* at = a + ((size_t)(n*NB_+pb)*K_ + k0)*32 + px;
    float aw0 = u2f(at[0])*w0;  s_aw[0][p] = aw0; loc[0] += aw0;
    float aw1 = u2f(at[32])*w1; s_aw[1][p] = aw1; loc[1] += aw1;
    float aw2 = u2f(at[64])*w2; s_aw[2][p] = aw2; loc[2] += aw2;
    float aw3 = u2f(at[96])*w3; s_aw[3][p] = aw3; loc[3] += aw3;
  }
  #pragma unroll
  for (int o=32;o>0;o>>=1){
    #pragma unroll
    for (int j=0;j<4;++j) loc[j] += __shfl_down(loc[j],o);
  }
  if ((t&63) == 0){
    #pragma unroll
    for (int j=0;j<4;++j) s_saw[j][t>>6] = loc[j];
  }
  __syncthreads();

  int cg = t&31, pg = t>>5;                      // thread: 4 channels, pixel stride 8
  const bf16* xb = xnT + (size_t)n*P_*C_ + cg*4;
  float va[4][4];
  #pragma unroll
  for (int j=0;j<4;++j){ va[j][0]=0;va[j][1]=0;va[j][2]=0;va[j][3]=0; }
  #pragma unroll 2
  for (int p=pg;p<P_;p+=8){
    ushort4 xv = *(const ushort4*)(xb + (size_t)p*C_);
    float f0=u2f(xv.x), f1=u2f(xv.y), f2=u2f(xv.z), f3=u2f(xv.w);
    #pragma unroll
    for (int j=0;j<4;++j){
      float wj = s_aw[j][p];
      va[j][0] += f0*wj; va[j][1] += f1*wj; va[j][2] += f2*wj; va[j][3] += f3*wj;
    }
  }
  float sumaw[4];
  #pragma unroll
  for (int j=0;j<4;++j) sumaw[j] = s_saw[j][0]+s_saw[j][1]+s_saw[j][2]+s_saw[j][3];

  #pragma unroll
  for (int j=0;j<4;++j){
    __syncthreads();
    s_red[pg][cg][0]=va[j][0]; s_red[pg][cg][1]=va[j][1];
    s_red[pg][cg][2]=va[j][2]; s_red[pg][cg][3]=va[j][3];
    __syncthreads();
    if (t < C_){
      float v = 0.f;
      #pragma unroll
      for (int gg=0;gg<8;++gg) v += ((const float*)s_red)[gg*128 + t];
      float cv = f32 ? ((const float*)cen)[(k0+j)*C_ + t] : b2f(((const bf16*)cen)[(k0+j)*C_ + t]);
      vlad[((size_t)n*K_+k0+j)*C_ + t] = v - cv * sumaw[j];
    }
  }
}

// ---------- K5: intra-norm * cluster_weights, global L2 norm, store ----------
__global__ __launch_bounds__(256) void k_final(const float* __restrict__ vlad,
                                               const void* __restrict__ clw,
                                               const int* __restrict__ flag,
                                               void* __restrict__ out){
  __shared__ float s_v[K_*C_];
  __shared__ float s_ssk[K_];
  __shared__ float s_scale[K_];
  __shared__ float s_gs;
  int n = blockIdx.x, t = threadIdx.x;
  int f32 = flag[0];
  const float* vp = vlad + (size_t)n*K_*C_;
  for (int i=t;i<K_*C_;i+=256) s_v[i] = vp[i];
  __syncthreads();
  int k = t >> 2, q = t & 3;
  float ss = 0.f;
  for (int m=0;m<32;++m){ float v = s_v[k*C_ + q + 4*m]; ss += v*v; }
  ss += __shfl_down(ss, 2);
  ss += __shfl_down(ss, 1);
  if (q == 0) s_ssk[k] = ss;
  __syncthreads();
  if (t < K_){
    float cw = f32 ? ((const float*)clw)[t] : b2f(((const bf16*)clw)[t]);
    s_scale[t] = cw / fmaxf(sqrtf(s_ssk[t]), 1e-12f);
  }
  __syncthreads();
  if (t == 0){
    float gss = 0.f;
    for (int kk=0;kk<K_;++kk) gss += s_ssk[kk]*s_scale[kk]*s_scale[kk];
    s_gs = 1.f / fmaxf(sqrtf(gss), 1e-12f);
  }
  __syncthreads();
  float gsc = s_gs;
  if (f32){
    float* op = (float*)out + (size_t)n*K_*C_;
    for (int i=t;i<K_*C_;i+=256) op[i] = s_v[i]*s_scale[i>>7]*gsc;
  } else {
    bf16* op = (bf16*)out + (size_t)n*K_*C_;
    for (int i=t;i<K_*C_;i+=256) op[i] = __float2bfloat16(s_v[i]*s_scale[i>>7]*gsc);
  }
}

extern "C" void kernel_launch(void* const* d_in, const int* in_sizes, int n_in,
                              void* d_out, int out_size, void* d_ws, size_t ws_size,
                              hipStream_t stream){
  const void* x   = d_in[0];
  const void* cen = d_in[1];
  const void* cvw = d_in[2];
  const void* csw = d_in[3];
  const void* caw = d_in[4];
  const void* clw = d_in[5];

  char* ws = (char*)d_ws;
  int*  flag  = (int*)ws;              ws += 256;
  bf16* Wall  = (bf16*)ws;             ws += (size_t)M_*C_*2;        // 128 KB
  bf16* xnT   = (bf16*)ws;             ws += (size_t)N_*P_*C_*2;     // 18.87 MB
  unsigned short* a = (unsigned short*)ws;  ws += (size_t)N_*K_*P_*2;    //  9.44 MB (tiled)
  unsigned short* g = (unsigned short*)ws;  ws += (size_t)N_*192*P_*2;   // 28.31 MB (tiled)
  float* sal  = (float*)ws;            ws += (size_t)N_*K_*R_*4;     //  0.17 MB
  float* vlad = (float*)ws;            ws += (size_t)N_*K_*C_*4;     //  1.05 MB

  k_probe <<<dim3(1),           256, 0, stream>>>((const unsigned short*)x, flag);
  k_wall  <<<dim3(M_*C_/256),   256, 0, stream>>>(cvw, csw, caw, flag, Wall);
  k_norm  <<<dim3((N_*P_)/256), 256, 0, stream>>>(x, flag, xnT);
  k_gemm  <<<dim3(NB_, N_),     256, 0, stream>>>(Wall, xnT, a, g);
  k_sal2  <<<dim3(K_, N_),      256, 0, stream>>>(g, sal);
  k_vlad  <<<dim3(K_/4, N_),    256, 0, stream>>>(xnT, a, sal, cen, flag, vlad);
  k_final <<<dim3(N_),          256, 0, stream>>>(vlad, clw, flag, d_out);
}

// Round 6
// 238.293 us; speedup vs baseline: 1.0640x; 1.0640x over previous
//
#include <hip/hip_runtime.h>
#include <hip/hip_bf16.h>

#define N_ 32
#define C_ 128
#define H_ 48
#define W_ 48
#define P_ (H_*W_)   // 2304
#define K_ 64
#define S_ 4
#define L_ 3
#define R_ 21
#define NB_ 72       // P_/32 pixel tiles per image
#define M_ 512       // total logit rows
#define CH_ 18       // vlad chunks (128 px each)

typedef __hip_bfloat16 bf16;
typedef __attribute__((ext_vector_type(8))) short   bf16x8;
typedef __attribute__((ext_vector_type(8))) unsigned short u16x8;
typedef __attribute__((ext_vector_type(4))) float   f32x4;

__device__ __forceinline__ float b2f(bf16 v){ return __bfloat162float(v); }
__device__ __forceinline__ float u2f(unsigned short u){
  union { unsigned i; float f; } v; v.i = ((unsigned)u) << 16; return v.f;
}
__device__ __forceinline__ unsigned short f2u(float f){
  bf16 h = __float2bfloat16(f);
  return *(unsigned short*)&h;
}

// ---------- dtype probe: flag=1 if inputs are fp32, 0 if bf16 ----------
__global__ __launch_bounds__(256) void k_probe(const unsigned short* __restrict__ xb,
                                               int* __restrict__ flag){
  int t = threadIdx.x;
  int weird = 0;
  for (int i = t; i < 4096; i += 256){
    int e = (xb[i] >> 7) & 0xFF;
    if (e >= 0x8E) weird++;
  }
  __shared__ int s[256];
  s[t] = weird; __syncthreads();
  for (int o = 128; o > 0; o >>= 1){ if (t < o) s[t] += s[t+o]; __syncthreads(); }
  if (t == 0) flag[0] = (s[0] > 64) ? 1 : 0;
}

// ---------- build Wall[512][128] bf16 ----------
__global__ __launch_bounds__(256) void k_wall(const void* __restrict__ cvw, const void* __restrict__ csw,
                                              const void* __restrict__ caw, const int* __restrict__ flag,
                                              bf16* __restrict__ Wall){
  int i = blockIdx.x*256 + threadIdx.x;
  int f32 = flag[0];
  float v;
  if (i < 8192)       v = f32 ? ((const float*)cvw)[i]        : b2f(((const bf16*)cvw)[i]);
  else if (i < 40960) v = f32 ? ((const float*)csw)[i-8192]   : b2f(((const bf16*)csw)[i-8192]);
  else                v = f32 ? ((const float*)caw)[i-40960]  : b2f(((const bf16*)caw)[i-40960]);
  Wall[i] = __float2bfloat16(v);
}

// ---------- K1: L2 norm -> xnT[n][p][c] (B-layout for c-contraction) AND xnC[n][c][p] (B-layout for p-contraction) ----------
__global__ __launch_bounds__(256) void k_norm(const void* __restrict__ x,
                                              const int* __restrict__ flag,
                                              bf16* __restrict__ xnT,
                                              bf16* __restrict__ xnC){
  int idx = blockIdx.x*256 + threadIdx.x;
  int n = idx / P_, p = idx - n*P_;
  int f32 = flag[0];
  float ss = 0.f;
  if (f32){
    const float* xc = (const float*)x + (size_t)n*C_*P_ + p;
    #pragma unroll 8
    for (int c=0;c<C_;++c){ float v = xc[(size_t)c*P_]; ss += v*v; }
    float invn = 1.f / fmaxf(sqrtf(ss), 1e-12f);
    bf16* xo = xnT + ((size_t)n*P_ + p)*C_;
    bf16* xq = xnC + (size_t)n*C_*P_ + p;
    for (int c8=0;c8<C_;c8+=8){
      u16x8 pk;
      #pragma unroll
      for (int j=0;j<8;++j) pk[j] = f2u(xc[(size_t)(c8+j)*P_] * invn);
      *(u16x8*)(xo + c8) = pk;
      #pragma unroll
      for (int j=0;j<8;++j) *(unsigned short*)(xq + (size_t)(c8+j)*P_) = pk[j];
    }
  } else {
    const bf16* xc = (const bf16*)x + (size_t)n*C_*P_ + p;
    #pragma unroll 8
    for (int c=0;c<C_;++c){ float v = b2f(xc[(size_t)c*P_]); ss += v*v; }
    float invn = 1.f / fmaxf(sqrtf(ss), 1e-12f);
    bf16* xo = xnT + ((size_t)n*P_ + p)*C_;
    bf16* xq = xnC + (size_t)n*C_*P_ + p;
    for (int c8=0;c8<C_;c8+=8){
      u16x8 pk;
      #pragma unroll
      for (int j=0;j<8;++j) pk[j] = f2u(b2f(xc[(size_t)(c8+j)*P_]) * invn);
      *(u16x8*)(xo + c8) = pk;
      #pragma unroll
      for (int j=0;j<8;++j) *(unsigned short*)(xq + (size_t)(c8+j)*P_) = pk[j];
    }
  }
}

// ---------- K2: fused 512-row MFMA GEMM; 320 rows -> LDS softmax; app rows stay in regs, LDS reused ----------
__global__ __launch_bounds__(256, 3) void k_gemm(const bf16* __restrict__ Wall,
                                                 const bf16* __restrict__ xnT,
                                                 unsigned short* __restrict__ a,
                                                 unsigned short* __restrict__ g){
  __shared__ __align__(16) char smem[320*34*4];          // 43520 B; reused as app staging
  float (*ldsL)[34] = (float(*)[34])smem;                // [320][34]
  unsigned short (*appS)[32] = (unsigned short(*)[32])smem; // [192][32] = 12288 B
  __shared__ float redA[32][8];
  __shared__ float redB[32][8];
  __shared__ __align__(16) unsigned short a_tile[K_*32];
  int n = blockIdx.y, pb = blockIdx.x;
  int p0 = pb*32;
  int t = threadIdx.x, wv = t>>6, l = t&63;

  int mrow = l&15, quad = l>>4;
  const bf16* Abase = Wall + ((size_t)(wv*128 + mrow))*C_ + quad*8;
  const bf16* Bbase = xnT + ((size_t)n*P_ + p0 + mrow)*C_ + quad*8;

  f32x4 acc[8][2];
  #pragma unroll
  for (int rt=0;rt<8;++rt){ acc[rt][0] = (f32x4){0,0,0,0}; acc[rt][1] = (f32x4){0,0,0,0}; }

  #pragma unroll
  for (int k0=0;k0<C_;k0+=32){
    bf16x8 b0 = *(const bf16x8*)(Bbase + k0);
    bf16x8 b1 = *(const bf16x8*)(Bbase + 16*C_ + k0);
    #pragma unroll
    for (int rt=0;rt<8;++rt){
      bf16x8 af = *(const bf16x8*)(Abase + (size_t)rt*16*C_ + k0);
      acc[rt][0] = __builtin_amdgcn_mfma_f32_16x16x32_bf16(af, b0, acc[rt][0], 0,0,0);
      acc[rt][1] = __builtin_amdgcn_mfma_f32_16x16x32_bf16(af, b1, acc[rt][1], 0,0,0);
    }
  }
  // C/D: col = lane&15, row = quad*4 + reg. Rows <320 to LDS; app rows stay in regs.
  #pragma unroll
  for (int rt=0;rt<8;++rt){
    int row0 = wv*128 + rt*16;
    if (row0 < 320){
      #pragma unroll
      for (int ct=0;ct<2;++ct)
        #pragma unroll
        for (int r=0;r<4;++r)
          ldsL[row0 + quad*4 + r][ct*16 + mrow] = acc[rt][ct][r];
    }
  }
  __syncthreads();

  // ---- softmax epilogue: thread t -> pixel px = t&31, cluster group g2 = t>>5 ----
  int px = t&31, g2 = t>>5;
  float sc[8];
  #pragma unroll
  for (int kk=0;kk<8;++kk) sc[kk] = ldsL[g2*8+kk][px];
  float pm = sc[0];
  #pragma unroll
  for (int kk=1;kk<8;++kk) pm = fmaxf(pm, sc[kk]);
  redA[px][g2] = pm;
  __syncthreads();
  float m = redA[px][0];
  #pragma unroll
  for (int i=1;i<8;++i) m = fmaxf(m, redA[px][i]);
  float ps = 0.f;
  #pragma unroll
  for (int kk=0;kk<8;++kk) ps += __expf(sc[kk]-m);
  redB[px][g2] = ps;
  __syncthreads();
  float Z = 0.f;
  #pragma unroll
  for (int i=0;i<8;++i) Z += redB[px][i];
  float invZ = 1.f / Z;

  #pragma unroll
  for (int kk=0;kk<8;++kk){
    int k = g2*8 + kk;
    float s0 = sc[kk];
    float sh0 = ldsL[64 + k*4 + 0][px];
    float sh1 = ldsL[64 + k*4 + 1][px];
    float sh2 = ldsL[64 + k*4 + 2][px];
    float sh3 = ldsL[64 + k*4 + 3][px];
    float m2 = fmaxf(fmaxf(fmaxf(fmaxf(s0, sh0), sh1), sh2), sh3);
    float e0 = __expf(s0-m2);
    float den = e0 + __expf(sh0-m2) + __expf(sh1-m2) + __expf(sh2-m2) + __expf(sh3-m2);
    a_tile[k*32 + px] = f2u(__expf(s0-m)*invZ * (e0/den));
  }
  __syncthreads();   // all ldsL reads done; a_tile complete

  size_t tile = (size_t)n*NB_ + pb;
  *(u16x8*)(a + tile*(K_*32) + t*8) = ((const u16x8*)a_tile)[t];

  // ---- app rows: regs -> reused LDS (bf16) ----
  #pragma unroll
  for (int rt=0;rt<8;++rt){
    int row0 = wv*128 + rt*16;
    if (row0 >= 320){
      int ar0 = row0 - 320 + quad*4;
      #pragma unroll
      for (int ct=0;ct<2;++ct)
        #pragma unroll
        for (int r=0;r<4;++r)
          appS[ar0 + r][ct*16 + mrow] = f2u(fmaxf(acc[rt][ct][r], 0.f));
    }
  }
  __syncthreads();
  // ---- coalesced tiled g store: 192*32 ushort = 768 u16x8 chunks ----
  unsigned short* gt = g + tile*(192*32);
  #pragma unroll
  for (int it=0;it<3;++it){
    int i = t + it*256;
    *(u16x8*)(gt + i*8) = ((const u16x8*)appS)[i];
  }
}

// ---------- K3: region sums from tiled g -> sal[n][k][21] ----------
__global__ __launch_bounds__(256) void k_sal2(const unsigned short* __restrict__ g,
                                              float* __restrict__ sal){
  int k = blockIdx.x, n = blockIdx.y, t = threadIdx.x;
  const unsigned short* gb = g + (size_t)n*NB_*(192*32);
  float acc[R_];
  #pragma unroll
  for (int r=0;r<R_;++r) acc[r] = 0.f;
  #pragma unroll
  for (int jj=0;jj<9;++jj){
    int p = t + jj*256;
    int pb = p>>5, px = p&31;
    int h = p/48, wc = p - h*48;
    const unsigned short* gt = gb + (size_t)pb*(192*32);
    acc[0] += u2f(gt[k*32 + px]);
    float v1 = u2f(gt[(64+k)*32 + px]);
    #pragma unroll
    for (int i=0;i<2;++i) if (h>=16*i && h<16*i+32)
      #pragma unroll
      for (int j=0;j<2;++j) if (wc>=16*j && wc<16*j+32) acc[1+2*i+j] += v1;
    float v2 = u2f(gt[(128+k)*32 + px]);
    #pragma unroll
    for (int i=0;i<4;++i) if (h>=10*i-1 && h<10*i+19)
      #pragma unroll
      for (int j=0;j<4;++j) if (wc>=10*j-1 && wc<10*j+19) acc[5+4*i+j] += v2;
  }
  #pragma unroll
  for (int r=0;r<R_;++r){
    float v = acc[r];
    #pragma unroll
    for (int o=32;o>0;o>>=1) v += __shfl_down(v, o);
    acc[r] = v;
  }
  __shared__ float s_part[4][R_];
  int wv = t>>6;
  if ((t&63) == 0){
    #pragma unroll
    for (int r=0;r<R_;++r) s_part[wv][r] = acc[r];
  }
  __syncthreads();
  if (t < R_)
    sal[((size_t)n*K_+k)*R_ + t] = s_part[0][t]+s_part[1][t]+s_part[2][t]+s_part[3][t];
}

// ---------- K4: vlad partials via MFMA. Block = (chunk of 128 px, n). ----------
// vladPart[n][ch][64][128] fp32, sumawPart[n][ch][64].
__global__ __launch_bounds__(256) void k_vlad(const bf16* __restrict__ xnC,
                                              const unsigned short* __restrict__ a,
                                              const float* __restrict__ sal,
                                              float* __restrict__ vladPart,
                                              float* __restrict__ sumawPart){
  __shared__ float s_sal[K_][R_];                    // 5376 B
  __shared__ __align__(16) unsigned short awL[4][K_][40];  // 20480 B (pad 40 -> 2-way free)
  __shared__ float s_part[4][K_];                    // 1024 B
  int chunk = blockIdx.x, n = blockIdx.y, t = threadIdx.x;
  int p0 = chunk*128;
  for (int i=t;i<K_*R_;i+=256) ((float*)s_sal)[i] = sal[(size_t)n*K_*R_ + i];
  __syncthreads();

  // build aw[k][p] bf16: thread owns px (pxl = t&127), half the clusters (khalf = t>>7)
  {
    int pxl = t & 127, khalf = t>>7;
    int pbl = pxl>>5, px = pxl&31;
    int p = p0 + pxl;
    int h = p/48, wc = p - h*48;
    bool h1[2], w1[2], h2[4], w2[4];
    #pragma unroll
    for (int i=0;i<2;++i){ h1[i] = (h>=16*i)&&(h<16*i+32); w1[i] = (wc>=16*i)&&(wc<16*i+32); }
    #pragma unroll
    for (int i=0;i<4;++i){ h2[i] = (h>=10*i-1)&&(h<10*i+19); w2[i] = (wc>=10*i-1)&&(wc<10*i+19); }
    const unsigned short* at = a + ((size_t)(n*NB_ + chunk*4 + pbl)*K_)*32 + px;
    #pragma unroll 4
    for (int kk=0;kk<32;++kk){
      int k = khalf*32 + kk;
      float w = s_sal[k][0];
      #pragma unroll
      for (int i=0;i<2;++i) if (h1[i])
        #pragma unroll
        for (int j=0;j<2;++j) if (w1[j]) w += s_sal[k][1+2*i+j];
      #pragma unroll
      for (int i=0;i<4;++i) if (h2[i])
        #pragma unroll
        for (int j=0;j<4;++j) if (w2[j]) w += s_sal[k][5+4*i+j];
      awL[pbl][k][px] = f2u(u2f(at[k*32]) * w);
    }
  }
  __syncthreads();
  // per-quarter row sums for sumaw
  {
    int k = t&63, qr = t>>6;
    float s = 0.f;
    #pragma unroll 8
    for (int j=0;j<32;++j) s += u2f(awL[qr][k][j]);
    s_part[qr][k] = s;
  }
  __syncthreads();

  // MFMA: D[64k][128c] over 4 ksteps of 32 px. Wave wv owns cols wv*32..+31.
  int wv = t>>6, l = t&63, mrow = l&15, quad = l>>4;
  f32x4 acc[4][2];
  #pragma unroll
  for (int mt=0;mt<4;++mt){ acc[mt][0] = (f32x4){0,0,0,0}; acc[mt][1] = (f32x4){0,0,0,0}; }
  const bf16* Bb = xnC + ((size_t)n*C_ + wv*32 + mrow)*P_ + p0 + quad*8;
  #pragma unroll
  for (int ks=0;ks<4;++ks){
    bf16x8 b0 = *(const bf16x8*)(Bb + ks*32);
    bf16x8 b1 = *(const bf16x8*)(Bb + (size_t)16*P_ + ks*32);
    #pragma unroll
    for (int mt=0;mt<4;++mt){
      bf16x8 af = *(const bf16x8*)((const bf16*)&awL[ks][mt*16 + mrow][quad*8]);
      acc[mt][0] = __builtin_amdgcn_mfma_f32_16x16x32_bf16(af, b0, acc[mt][0], 0,0,0);
      acc[mt][1] = __builtin_amdgcn_mfma_f32_16x16x32_bf16(af, b1, acc[mt][1], 0,0,0);
    }
  }
  float* vp = vladPart + ((size_t)(n*CH_ + chunk))*(K_*C_);
  #pragma unroll
  for (int mt=0;mt<4;++mt){
    #pragma unroll
    for (int ct=0;ct<2;++ct){
      int c = wv*32 + ct*16 + mrow;
      #pragma unroll
      for (int r=0;r<4;++r){
        int k = mt*16 + quad*4 + r;
        vp[k*C_ + c] = acc[mt][ct][r];
      }
    }
  }
  if (t < K_)
    sumawPart[((size_t)n*CH_ + chunk)*K_ + t] = s_part[0][t]+s_part[1][t]+s_part[2][t]+s_part[3][t];
}

// ---------- K5: reduce chunks, -cen*sumaw, intra-norm * clw, global norm, store ----------
__global__ __launch_bounds__(256) void k_final(const float* __restrict__ vladPart,
                                               const float* __restrict__ sumawPart,
                                               const void* __restrict__ cen,
                                               const void* __restrict__ clw,
                                               const int* __restrict__ flag,
                                               void* __restrict__ out){
  __shared__ float s_v[K_*C_];
  __shared__ float s_sumaw[K_];
  __shared__ float s_ssk[K_];
  __shared__ float s_scale[K_];
  __shared__ float s_gs;
  int n = blockIdx.x, t = threadIdx.x;
  int f32 = flag[0];
  if (t < K_){
    float s = 0.f;
    #pragma unroll
    for (int ch=0;ch<CH_;++ch) s += sumawPart[((size_t)n*CH_ + ch)*K_ + t];
    s_sumaw[t] = s;
  }
  __syncthreads();
  const float* vp = vladPart + (size_t)n*CH_*(K_*C_);
  for (int i=t;i<K_*C_;i+=256){
    float v = 0.f;
    #pragma unroll
    for (int ch=0;ch<CH_;++ch) v += vp[(size_t)ch*(K_*C_) + i];
    float cv = f32 ? ((const float*)cen)[i] : b2f(((const bf16*)cen)[i]);
    s_v[i] = v - cv * s_sumaw[i>>7];
  }
  __syncthreads();
  int k = t >> 2, q = t & 3;
  float ss = 0.f;
  for (int mm=0;mm<32;++mm){ float v = s_v[k*C_ + q + 4*mm]; ss += v*v; }
  ss += __shfl_down(ss, 2);
  ss += __shfl_down(ss, 1);
  if (q == 0) s_ssk[k] = ss;
  __syncthreads();
  if (t < K_){
    float cw = f32 ? ((const float*)clw)[t] : b2f(((const bf16*)clw)[t]);
    s_scale[t] = cw / fmaxf(sqrtf(s_ssk[t]), 1e-12f);
  }
  __syncthreads();
  if (t == 0){
    float gss = 0.f;
    for (int kk=0;kk<K_;++kk) gss += s_ssk[kk]*s_scale[kk]*s_scale[kk];
    s_gs = 1.f / fmaxf(sqrtf(gss), 1e-12f);
  }
  __syncthreads();
  float gsc = s_gs;
  if (f32){
    float* op = (float*)out + (size_t)n*K_*C_;
    for (int i=t;i<K_*C_;i+=256) op[i] = s_v[i]*s_scale[i>>7]*gsc;
  } else {
    bf16* op = (bf16*)out + (size_t)n*K_*C_;
    for (int i=t;i<K_*C_;i+=256) op[i] = __float2bfloat16(s_v[i]*s_scale[i>>7]*gsc);
  }
}

extern "C" void kernel_launch(void* const* d_in, const int* in_sizes, int n_in,
                              void* d_out, int out_size, void* d_ws, size_t ws_size,
                              hipStream_t stream){
  const void* x   = d_in[0];
  const void* cen = d_in[1];
  const void* cvw = d_in[2];
  const void* csw = d_in[3];
  const void* caw = d_in[4];
  const void* clw = d_in[5];

  char* ws = (char*)d_ws;
  int*  flag  = (int*)ws;              ws += 256;
  bf16* Wall  = (bf16*)ws;             ws += (size_t)M_*C_*2;        // 128 KB
  bf16* xnT   = (bf16*)ws;             ws += (size_t)N_*P_*C_*2;     // 18.87 MB
  bf16* xnC   = (bf16*)ws;             ws += (size_t)N_*C_*P_*2;     // 18.87 MB
  unsigned short* a = (unsigned short*)ws;  ws += (size_t)N_*K_*P_*2;    // 9.44 MB (tiled)
  float* sal  = (float*)ws;            ws += (size_t)N_*K_*R_*4;     // 0.17 MB
  // union: g (28.31 MB) is dead after k_sal2; vladPart+sumawPart (19.0 MB) overlay it
  char* un = ws;                       ws += (size_t)N_*192*P_*2;
  unsigned short* g = (unsigned short*)un;
  float* vladPart   = (float*)un;                                    // 18.87 MB
  float* sumawPart  = (float*)(un + (size_t)N_*CH_*K_*C_*4);         // 0.147 MB

  k_probe <<<dim3(1),           256, 0, stream>>>((const unsigned short*)x, flag);
  k_wall  <<<dim3(M_*C_/256),   256, 0, stream>>>(cvw, csw, caw, flag, Wall);
  k_norm  <<<dim3((N_*P_)/256), 256, 0, stream>>>(x, flag, xnT, xnC);
  k_gemm  <<<dim3(NB_, N_),     256, 0, stream>>>(Wall, xnT, a, g);
  k_sal2  <<<dim3(K_, N_),      256, 0, stream>>>(g, sal);
  k_vlad  <<<dim3(CH_, N_),     256, 0, stream>>>(xnC, a, sal, vladPart, sumawPart);
  k_final <<<dim3(N_),          256, 0, stream>>>(vladPart, sumawPart, cen, clw, flag, d_out);
}

// Round 7
// 226.120 us; speedup vs baseline: 1.1212x; 1.0538x over previous
//
#include <hip/hip_runtime.h>
#include <hip/hip_bf16.h>

#define N_ 32
#define C_ 128
#define H_ 48
#define W_ 48
#define P_ (H_*W_)   // 2304
#define K_ 64
#define S_ 4
#define L_ 3
#define R_ 21
#define NB_ 72       // P_/32 pixel tiles per image
#define M_ 512       // total logit rows
#define CH_ 18       // vlad chunks (128 px each)

typedef __hip_bfloat16 bf16;
typedef __attribute__((ext_vector_type(8))) short   bf16x8;
typedef __attribute__((ext_vector_type(8))) unsigned short u16x8;
typedef __attribute__((ext_vector_type(4))) float   f32x4;

__device__ __forceinline__ float b2f(bf16 v){ return __bfloat162float(v); }
__device__ __forceinline__ float u2f(unsigned short u){
  union { unsigned i; float f; } v; v.i = ((unsigned)u) << 16; return v.f;
}
__device__ __forceinline__ unsigned short f2u(float f){
  bf16 h = __float2bfloat16(f);
  return *(unsigned short*)&h;
}

// ---------- dtype probe: flag=1 if inputs are fp32, 0 if bf16 ----------
__global__ __launch_bounds__(256) void k_probe(const unsigned short* __restrict__ xb,
                                               int* __restrict__ flag){
  int t = threadIdx.x;
  int weird = 0;
  for (int i = t; i < 4096; i += 256){
    int e = (xb[i] >> 7) & 0xFF;
    if (e >= 0x8E) weird++;
  }
  __shared__ int s[256];
  s[t] = weird; __syncthreads();
  for (int o = 128; o > 0; o >>= 1){ if (t < o) s[t] += s[t+o]; __syncthreads(); }
  if (t == 0) flag[0] = (s[0] > 64) ? 1 : 0;
}

// ---------- build Wall[512][128] bf16 ----------
__global__ __launch_bounds__(256) void k_wall(const void* __restrict__ cvw, const void* __restrict__ csw,
                                              const void* __restrict__ caw, const int* __restrict__ flag,
                                              bf16* __restrict__ Wall){
  int i = blockIdx.x*256 + threadIdx.x;
  int f32 = flag[0];
  float v;
  if (i < 8192)       v = f32 ? ((const float*)cvw)[i]        : b2f(((const bf16*)cvw)[i]);
  else if (i < 40960) v = f32 ? ((const float*)csw)[i-8192]   : b2f(((const bf16*)csw)[i-8192]);
  else                v = f32 ? ((const float*)caw)[i-40960]  : b2f(((const bf16*)caw)[i-40960]);
  Wall[i] = __float2bfloat16(v);
}

// ---------- K1: L2 norm, 2 pixels/thread -> xnT[n][p][c] and xnC[n][c][p] ----------
__global__ __launch_bounds__(256) void k_norm(const void* __restrict__ x,
                                              const int* __restrict__ flag,
                                              bf16* __restrict__ xnT,
                                              bf16* __restrict__ xnC){
  int idx = blockIdx.x*256 + threadIdx.x;        // pair index: n*(P/2) + q
  int n = idx / (P_/2), q = idx - n*(P_/2);
  int p = q*2;
  int f32 = flag[0];
  float ss0 = 0.f, ss1 = 0.f;
  bf16* xo0 = xnT + ((size_t)n*P_ + p)*C_;
  bf16* xo1 = xo0 + C_;
  unsigned* xq = (unsigned*)(xnC + (size_t)n*C_*P_ + p);   // stride P_/2 u32
  if (f32){
    const float* xc = (const float*)x + (size_t)n*C_*P_ + p;
    #pragma unroll 8
    for (int c=0;c<C_;++c){
      float2 v = *(const float2*)(xc + (size_t)c*P_);
      ss0 += v.x*v.x; ss1 += v.y*v.y;
    }
    float i0 = 1.f/fmaxf(sqrtf(ss0),1e-12f), i1 = 1.f/fmaxf(sqrtf(ss1),1e-12f);
    for (int c8=0;c8<C_;c8+=8){
      u16x8 pk0, pk1;
      #pragma unroll
      for (int j=0;j<8;++j){
        float2 v = *(const float2*)(xc + (size_t)(c8+j)*P_);
        unsigned short a0 = f2u(v.x*i0), a1 = f2u(v.y*i1);
        pk0[j]=a0; pk1[j]=a1;
        xq[(size_t)(c8+j)*(P_/2)] = (unsigned)a0 | ((unsigned)a1<<16);
      }
      *(u16x8*)(xo0+c8) = pk0; *(u16x8*)(xo1+c8) = pk1;
    }
  } else {
    const unsigned* xc = (const unsigned*)((const bf16*)x + (size_t)n*C_*P_ + p);
    #pragma unroll 8
    for (int c=0;c<C_;++c){
      unsigned v = xc[(size_t)c*(P_/2)];
      float v0 = u2f(v&0xffff), v1 = u2f(v>>16);
      ss0 += v0*v0; ss1 += v1*v1;
    }
    float i0 = 1.f/fmaxf(sqrtf(ss0),1e-12f), i1 = 1.f/fmaxf(sqrtf(ss1),1e-12f);
    for (int c8=0;c8<C_;c8+=8){
      u16x8 pk0, pk1;
      #pragma unroll
      for (int j=0;j<8;++j){
        unsigned v = xc[(size_t)(c8+j)*(P_/2)];
        unsigned short a0 = f2u(u2f(v&0xffff)*i0), a1 = f2u(u2f(v>>16)*i1);
        pk0[j]=a0; pk1[j]=a1;
        xq[(size_t)(c8+j)*(P_/2)] = (unsigned)a0 | ((unsigned)a1<<16);
      }
      *(u16x8*)(xo0+c8) = pk0; *(u16x8*)(xo1+c8) = pk1;
    }
  }
}

// ---------- K2: fused 512-row MFMA GEMM + softmax + region-sum epilogue ----------
// grid (NB_=72, N_=32), 4 waves. Wave w owns rows [w*128, w*128+128).
__global__ __launch_bounds__(256, 3) void k_gemm(const bf16* __restrict__ Wall,
                                                 const bf16* __restrict__ xnT,
                                                 unsigned short* __restrict__ a,
                                                 float* __restrict__ salPart){
  __shared__ __align__(16) char smem[320*34*4];            // 43520 B; reused as appS
  float (*ldsL)[34] = (float(*)[34])smem;                  // [320][34]
  unsigned short (*appS)[36] = (unsigned short(*)[36])smem;// [192][36] = 13824 B
  __shared__ float redA[32][8];
  __shared__ float redB[32][8];
  __shared__ __align__(16) unsigned short a_tile[K_*32];
  int n = blockIdx.y, pb = blockIdx.x;
  int p0 = pb*32;
  int t = threadIdx.x, wv = t>>6, l = t&63;

  int mrow = l&15, quad = l>>4;
  const bf16* Abase = Wall + ((size_t)(wv*128 + mrow))*C_ + quad*8;
  const bf16* Bbase = xnT + ((size_t)n*P_ + p0 + mrow)*C_ + quad*8;

  f32x4 acc[8][2];
  #pragma unroll
  for (int rt=0;rt<8;++rt){ acc[rt][0] = (f32x4){0,0,0,0}; acc[rt][1] = (f32x4){0,0,0,0}; }

  #pragma unroll
  for (int k0=0;k0<C_;k0+=32){
    bf16x8 b0 = *(const bf16x8*)(Bbase + k0);
    bf16x8 b1 = *(const bf16x8*)(Bbase + 16*C_ + k0);
    #pragma unroll
    for (int rt=0;rt<8;++rt){
      bf16x8 af = *(const bf16x8*)(Abase + (size_t)rt*16*C_ + k0);
      acc[rt][0] = __builtin_amdgcn_mfma_f32_16x16x32_bf16(af, b0, acc[rt][0], 0,0,0);
      acc[rt][1] = __builtin_amdgcn_mfma_f32_16x16x32_bf16(af, b1, acc[rt][1], 0,0,0);
    }
  }
  // C/D: col = lane&15, row = quad*4 + reg. Rows <320 -> LDS; app rows stay in regs.
  #pragma unroll
  for (int rt=0;rt<8;++rt){
    int row0 = wv*128 + rt*16;
    if (row0 < 320){
      #pragma unroll
      for (int ct=0;ct<2;++ct)
        #pragma unroll
        for (int r=0;r<4;++r)
          ldsL[row0 + quad*4 + r][ct*16 + mrow] = acc[rt][ct][r];
    }
  }
  __syncthreads();

  // ---- softmax: thread t -> pixel px = t&31, cluster group g2 = t>>5 ----
  int px = t&31, g2 = t>>5;
  float sc[8];
  #pragma unroll
  for (int kk=0;kk<8;++kk) sc[kk] = ldsL[g2*8+kk][px];
  float pm = sc[0];
  #pragma unroll
  for (int kk=1;kk<8;++kk) pm = fmaxf(pm, sc[kk]);
  redA[px][g2] = pm;
  __syncthreads();
  float m = redA[px][0];
  #pragma unroll
  for (int i=1;i<8;++i) m = fmaxf(m, redA[px][i]);
  float ps = 0.f;
  #pragma unroll
  for (int kk=0;kk<8;++kk) ps += __expf(sc[kk]-m);
  redB[px][g2] = ps;
  __syncthreads();
  float Z = 0.f;
  #pragma unroll
  for (int i=0;i<8;++i) Z += redB[px][i];
  float invZ = 1.f / Z;

  #pragma unroll
  for (int kk=0;kk<8;++kk){
    int k = g2*8 + kk;
    float s0 = sc[kk];
    float sh0 = ldsL[64 + k*4 + 0][px];
    float sh1 = ldsL[64 + k*4 + 1][px];
    float sh2 = ldsL[64 + k*4 + 2][px];
    float sh3 = ldsL[64 + k*4 + 3][px];
    float m2 = fmaxf(fmaxf(fmaxf(fmaxf(s0, sh0), sh1), sh2), sh3);
    float e0 = __expf(s0-m2);
    float den = e0 + __expf(sh0-m2) + __expf(sh1-m2) + __expf(sh2-m2) + __expf(sh3-m2);
    a_tile[k*32 + px] = f2u(__expf(s0-m)*invZ * (e0/den));
  }
  __syncthreads();   // all ldsL reads done; a_tile complete

  size_t tile = (size_t)n*NB_ + pb;
  *(u16x8*)(a + tile*(K_*32) + t*8) = ((const u16x8*)a_tile)[t];

  // ---- app rows (relu, bf16) -> appS (overlays ldsL) ----
  #pragma unroll
  for (int rt=0;rt<8;++rt){
    int row0 = wv*128 + rt*16;
    if (row0 >= 320){
      int ar0 = row0 - 320 + quad*4;
      #pragma unroll
      for (int ct=0;ct<2;++ct)
        #pragma unroll
        for (int r=0;r<4;++r)
          appS[ar0 + r][ct*16 + mrow] = f2u(fmaxf(acc[rt][ct][r], 0.f));
    }
  }
  __syncthreads();

  // ---- region sums: wave qsel handles level-slice for its k = t&63 ----
  int qsel = wv, k = t&63;
  int rowbase = (qsel==0) ? k : (qsel==1 ? 64+k : 128+k);
  const unsigned* aps = (const unsigned*)&appS[rowbase][0];
  float racc[8];
  #pragma unroll
  for (int r=0;r<8;++r) racc[r] = 0.f;
  #pragma unroll
  for (int e=0;e<16;++e){
    unsigned pr = aps[e];
    #pragma unroll
    for (int half=0;half<2;++half){
      float v = u2f(half ? (unsigned short)(pr>>16) : (unsigned short)(pr&0xffff));
      int p = p0 + 2*e + half;
      int h = p/48, wc = p - h*48;
      if (qsel == 0){
        racc[0] += v;
      } else if (qsel == 1){
        bool hA = h < 32, hB = h >= 16;
        bool wA = wc < 32, wB = wc >= 16;
        racc[0] += (hA&&wA)?v:0.f; racc[1] += (hA&&wB)?v:0.f;
        racc[2] += (hB&&wA)?v:0.f; racc[3] += (hB&&wB)?v:0.f;
      } else {
        int i0 = (qsel==2)?0:2;
        bool hA = (h>=10*i0-1)&&(h<10*i0+19);
        bool hB = (h>=10*(i0+1)-1)&&(h<10*(i0+1)+19);
        #pragma unroll
        for (int j=0;j<4;++j){
          bool wj = (wc>=10*j-1)&&(wc<10*j+19);
          racc[j]   += (hA&&wj)?v:0.f;
          racc[4+j] += (hB&&wj)?v:0.f;
        }
      }
    }
  }
  float* sp = salPart + tile*(K_*R_) + k*R_;
  if (qsel == 0){
    sp[0] = racc[0];
  } else if (qsel == 1){
    #pragma unroll
    for (int r=0;r<4;++r) sp[1+r] = racc[r];
  } else if (qsel == 2){
    #pragma unroll
    for (int r=0;r<8;++r) sp[5+r] = racc[r];
  } else {
    #pragma unroll
    for (int r=0;r<8;++r) sp[13+r] = racc[r];
  }
}

// ---------- K3: reduce 72 tile partials -> sal[n][k][21] ----------
__global__ __launch_bounds__(256) void k_salred(const float* __restrict__ salPart,
                                                float* __restrict__ sal){
  int tid = blockIdx.x*256 + threadIdx.x;
  if (tid >= N_*K_*R_) return;
  int n = tid / (K_*R_), i = tid - n*(K_*R_);
  const float* sp = salPart + (size_t)n*NB_*(K_*R_) + i;
  float s = 0.f;
  #pragma unroll 8
  for (int b=0;b<NB_;++b) s += sp[(size_t)b*(K_*R_)];
  sal[tid] = s;
}

// ---------- K4: vlad partials via MFMA. Block = (chunk of 128 px, n). ----------
__global__ __launch_bounds__(256) void k_vlad(const bf16* __restrict__ xnC,
                                              const unsigned short* __restrict__ a,
                                              const float* __restrict__ sal,
                                              float* __restrict__ vladPart,
                                              float* __restrict__ sumawPart){
  __shared__ float s_sal[K_][R_];                    // 5376 B
  __shared__ __align__(16) unsigned short awL[4][K_][40];  // 20480 B
  __shared__ float s_part[4][K_];                    // 1024 B
  int chunk = blockIdx.x, n = blockIdx.y, t = threadIdx.x;
  int p0 = chunk*128;
  for (int i=t;i<K_*R_;i+=256) ((float*)s_sal)[i] = sal[(size_t)n*K_*R_ + i];
  __syncthreads();

  {
    int pxl = t & 127, khalf = t>>7;
    int pbl = pxl>>5, px = pxl&31;
    int p = p0 + pxl;
    int h = p/48, wc = p - h*48;
    bool h1[2], w1[2], h2[4], w2[4];
    #pragma unroll
    for (int i=0;i<2;++i){ h1[i] = (h>=16*i)&&(h<16*i+32); w1[i] = (wc>=16*i)&&(wc<16*i+32); }
    #pragma unroll
    for (int i=0;i<4;++i){ h2[i] = (h>=10*i-1)&&(h<10*i+19); w2[i] = (wc>=10*i-1)&&(wc<10*i+19); }
    const unsigned short* at = a + ((size_t)(n*NB_ + chunk*4 + pbl)*K_)*32 + px;
    #pragma unroll 4
    for (int kk=0;kk<32;++kk){
      int k = khalf*32 + kk;
      float w = s_sal[k][0];
      #pragma unroll
      for (int i=0;i<2;++i) if (h1[i])
        #pragma unroll
        for (int j=0;j<2;++j) if (w1[j]) w += s_sal[k][1+2*i+j];
      #pragma unroll
      for (int i=0;i<4;++i) if (h2[i])
        #pragma unroll
        for (int j=0;j<4;++j) if (w2[j]) w += s_sal[k][5+4*i+j];
      awL[pbl][k][px] = f2u(u2f(at[k*32]) * w);
    }
  }
  __syncthreads();
  {
    int k = t&63, qr = t>>6;
    float s = 0.f;
    #pragma unroll 8
    for (int j=0;j<32;++j) s += u2f(awL[qr][k][j]);
    s_part[qr][k] = s;
  }
  __syncthreads();

  int wv = t>>6, l = t&63, mrow = l&15, quad = l>>4;
  f32x4 acc[4][2];
  #pragma unroll
  for (int mt=0;mt<4;++mt){ acc[mt][0] = (f32x4){0,0,0,0}; acc[mt][1] = (f32x4){0,0,0,0}; }
  const bf16* Bb = xnC + ((size_t)n*C_ + wv*32 + mrow)*P_ + p0 + quad*8;
  #pragma unroll
  for (int ks=0;ks<4;++ks){
    bf16x8 b0 = *(const bf16x8*)(Bb + ks*32);
    bf16x8 b1 = *(const bf16x8*)(Bb + (size_t)16*P_ + ks*32);
    #pragma unroll
    for (int mt=0;mt<4;++mt){
      bf16x8 af = *(const bf16x8*)((const bf16*)&awL[ks][mt*16 + mrow][quad*8]);
      acc[mt][0] = __builtin_amdgcn_mfma_f32_16x16x32_bf16(af, b0, acc[mt][0], 0,0,0);
      acc[mt][1] = __builtin_amdgcn_mfma_f32_16x16x32_bf16(af, b1, acc[mt][1], 0,0,0);
    }
  }
  float* vp = vladPart + ((size_t)(n*CH_ + chunk))*(K_*C_);
  #pragma unroll
  for (int mt=0;mt<4;++mt){
    #pragma unroll
    for (int ct=0;ct<2;++ct){
      int c = wv*32 + ct*16 + mrow;
      #pragma unroll
      for (int r=0;r<4;++r){
        int k = mt*16 + quad*4 + r;
        vp[k*C_ + c] = acc[mt][ct][r];
      }
    }
  }
  if (t < K_)
    sumawPart[((size_t)n*CH_ + chunk)*K_ + t] = s_part[0][t]+s_part[1][t]+s_part[2][t]+s_part[3][t];
}

// ---------- K5: parallel chunk reduction + centroid term -> vlad ----------
__global__ __launch_bounds__(256) void k_vred(const float* __restrict__ vladPart,
                                              const float* __restrict__ sumawPart,
                                              const void* __restrict__ cen,
                                              const int* __restrict__ flag,
                                              float* __restrict__ vlad){
  int tid = blockIdx.x*256 + threadIdx.x;       // < N_*K_*C_ = 262144
  int n = tid >> 13;                            // /8192
  int i = tid & 8191;
  int k = i >> 7;
  int f32 = flag[0];
  const float* vp = vladPart + (size_t)n*CH_*(K_*C_) + i;
  float s = 0.f;
  #pragma unroll
  for (int ch=0;ch<CH_;++ch) s += vp[(size_t)ch*(K_*C_)];
  float sw = 0.f;
  #pragma unroll
  for (int ch=0;ch<CH_;++ch) sw += sumawPart[((size_t)n*CH_ + ch)*K_ + k];
  float cv = f32 ? ((const float*)cen)[i] : b2f(((const bf16*)cen)[i]);
  vlad[tid] = s - cv*sw;
}

// ---------- K6: intra-norm * cluster_weights, global L2 norm, store ----------
__global__ __launch_bounds__(256) void k_final(const float* __restrict__ vlad,
                                               const void* __restrict__ clw,
                                               const int* __restrict__ flag,
                                               void* __restrict__ out){
  __shared__ float s_v[K_*C_];
  __shared__ float s_ssk[K_];
  __shared__ float s_scale[K_];
  __shared__ float s_gs;
  int n = blockIdx.x, t = threadIdx.x;
  int f32 = flag[0];
  const float* vp = vlad + (size_t)n*K_*C_;
  for (int i=t;i<K_*C_;i+=256) s_v[i] = vp[i];
  __syncthreads();
  int k = t >> 2, q = t & 3;
  float ss = 0.f;
  for (int mm=0;mm<32;++mm){ float v = s_v[k*C_ + q + 4*mm]; ss += v*v; }
  ss += __shfl_down(ss, 2);
  ss += __shfl_down(ss, 1);
  if (q == 0) s_ssk[k] = ss;
  __syncthreads();
  if (t < K_){
    float cw = f32 ? ((const float*)clw)[t] : b2f(((const bf16*)clw)[t]);
    s_scale[t] = cw / fmaxf(sqrtf(s_ssk[t]), 1e-12f);
  }
  __syncthreads();
  if (t == 0){
    float gss = 0.f;
    for (int kk=0;kk<K_;++kk) gss += s_ssk[kk]*s_scale[kk]*s_scale[kk];
    s_gs = 1.f / fmaxf(sqrtf(gss), 1e-12f);
  }
  __syncthreads();
  float gsc = s_gs;
  if (f32){
    float* op = (float*)out + (size_t)n*K_*C_;
    for (int i=t;i<K_*C_;i+=256) op[i] = s_v[i]*s_scale[i>>7]*gsc;
  } else {
    bf16* op = (bf16*)out + (size_t)n*K_*C_;
    for (int i=t;i<K_*C_;i+=256) op[i] = __float2bfloat16(s_v[i]*s_scale[i>>7]*gsc);
  }
}

extern "C" void kernel_launch(void* const* d_in, const int* in_sizes, int n_in,
                              void* d_out, int out_size, void* d_ws, size_t ws_size,
                              hipStream_t stream){
  const void* x   = d_in[0];
  const void* cen = d_in[1];
  const void* cvw = d_in[2];
  const void* csw = d_in[3];
  const void* caw = d_in[4];
  const void* clw = d_in[5];

  char* ws = (char*)d_ws;
  int*  flag  = (int*)ws;              ws += 256;
  bf16* Wall  = (bf16*)ws;             ws += (size_t)M_*C_*2;        // 128 KB
  bf16* xnT   = (bf16*)ws;             ws += (size_t)N_*P_*C_*2;     // 18.87 MB
  bf16* xnC   = (bf16*)ws;             ws += (size_t)N_*C_*P_*2;     // 18.87 MB
  char* aBuf  = ws;                    ws += (size_t)N_*K_*P_*2;     //  9.44 MB
  unsigned short* a = (unsigned short*)aBuf;
  float* vlad = (float*)aBuf;          // overlay: a dead after k_vlad, vlad written by k_vred
  float* sal  = (float*)ws;            ws += (size_t)N_*K_*R_*4;     //  0.17 MB
  // union: salPart (12.39 MB, dead after k_salred) / vladPart (18.87) + sumawPart
  char* un = ws;
  float* salPart   = (float*)un;
  float* vladPart  = (float*)un;
  float* sumawPart = (float*)(un + (size_t)N_*CH_*K_*C_*4);
  ws += (size_t)N_*CH_*K_*C_*4 + (size_t)N_*CH_*K_*4;                // 19.02 MB

  k_probe <<<dim3(1),              256, 0, stream>>>((const unsigned short*)x, flag);
  k_wall  <<<dim3(M_*C_/256),      256, 0, stream>>>(cvw, csw, caw, flag, Wall);
  k_norm  <<<dim3(N_*P_/2/256),    256, 0, stream>>>(x, flag, xnT, xnC);
  k_gemm  <<<dim3(NB_, N_),        256, 0, stream>>>(Wall, xnT, a, salPart);
  k_salred<<<dim3((N_*K_*R_+255)/256), 256, 0, stream>>>(salPart, sal);
  k_vlad  <<<dim3(CH_, N_),        256, 0, stream>>>(xnC, a, sal, vladPart, sumawPart);
  k_vred  <<<dim3(N_*K_*C_/256),   256, 0, stream>>>(vladPart, sumawPart, cen, flag, vlad);
  k_final <<<dim3(N_),             256, 0, stream>>>(vlad, clw, flag, d_out);
}